// Round 7
// baseline (145.831 us; speedup 1.0000x reference)
//
#include <hip/hip_runtime.h>
#include <hip/hip_bf16.h>
#include <math.h>

#define IN_DIM 128
#define OUT_DIM 64
#define NEG_SLOPE 0.01f
#define BCAP 1792          // slots per 64-node bucket (avg ~1023, 5-sigma ~1140; slot-guarded)
#define EPT 16             // edges per thread in part1 (4096 edges/block)

typedef __attribute__((ext_vector_type(8))) short bf8_t;   // 8 bf16 (4 VGPRs)
typedef __attribute__((ext_vector_type(4))) float f4_t;    // MFMA acc

struct FrontSm { int cntA[1024]; int gbase[1024]; };                       // 8 KB
struct TailSm  { uint2 se[BCAP]; unsigned p2s[BCAP]; float exs[BCAP];
                 int cnt_s[64]; int off_s[64]; float srs[64]; };           // ~29.4 KB
union SmU { FrontSm f; TailSm t; };

__device__ __forceinline__ bf8_t pack8(float4 a, float4 b) {
    union { bf8_t v; __hip_bfloat162 h[4]; } u;
    u.h[0] = __float22bfloat162_rn(make_float2(a.x, a.y));
    u.h[1] = __float22bfloat162_rn(make_float2(a.z, a.w));
    u.h[2] = __float22bfloat162_rn(make_float2(b.x, b.y));
    u.h[3] = __float22bfloat162_rn(make_float2(b.z, b.w));
    return u.v;
}

// ---------------- part1: bin 4096 edges into dst-buckets ----------------
__device__ void part1_body(int bid, int t,
    const int* __restrict__ src, const int* __restrict__ dst,
    int* __restrict__ bucket_cursor, unsigned* __restrict__ tmp, int E,
    int* cntA, int* gbase)
{
    const int base_e = bid * (256 * EPT);

    for (int b = t; b < 1024; b += 256) cntA[b] = 0;
    __syncthreads();

    unsigned pArr[EPT];
    unsigned short rArr[EPT];
    #pragma unroll
    for (int i = 0; i < EPT; i++) {
        int ei = base_e + i * 256 + t;
        if (ei < E) {
            int s = src[ei], d = dst[ei];
            int b = d >> 6;
            pArr[i] = ((unsigned)b << 22) | ((unsigned)s << 6) | (unsigned)(d & 63);
            rArr[i] = (unsigned short)atomicAdd(&cntA[b], 1);   // local rank
        } else {
            pArr[i] = 0xFFFFFFFFu;
        }
    }
    __syncthreads();

    for (int b = t; b < 1024; b += 256)
        if (cntA[b] > 0)
            gbase[b] = atomicAdd(&bucket_cursor[b], cntA[b]);
    __syncthreads();

    #pragma unroll
    for (int i = 0; i < EPT; i++) {
        unsigned p = pArr[i];
        if (p == 0xFFFFFFFFu) continue;
        int b = p >> 22;
        int slot = gbase[b] + rArr[i];
        if (slot < BCAP)
            tmp[(size_t)b * BCAP + slot] = p;
    }
}

// ---------------- gemm: MFMA, 64 nodes per block-equivalent ----------------
__device__ void gemm_body(int gb, int t,
    const float4* __restrict__ h4, const float4* __restrict__ W4,
    const float* __restrict__ Wattn,
    __hip_bfloat16* __restrict__ zb, float* __restrict__ s_l, float* __restrict__ s_r,
    int N)
{
    const int lane = t & 63;
    const int wv   = t >> 6;
    const int col  = lane & 15, quad = lane >> 4;
    const int n0   = gb * 64 + wv * 16;
    if (n0 >= N) return;   // returns from device fn only; callers re-sync after

    bf8_t bf[4][4];
    #pragma unroll
    for (int ns = 0; ns < 4; ns++) {
        const float4* wrow = W4 + (size_t)(ns * 16 + col) * (IN_DIM / 4);
        #pragma unroll
        for (int kb = 0; kb < 4; kb++) {
            float4 x = wrow[kb * 8 + quad * 2];
            float4 y = wrow[kb * 8 + quad * 2 + 1];
            bf[kb][ns] = pack8(x, y);
        }
    }

    const int  na = n0 + col;
    const bool nv = (na < N);
    const float4* hrow = h4 + (size_t)(nv ? na : 0) * (IN_DIM / 4);
    const float4 zero = make_float4(0.f, 0.f, 0.f, 0.f);

    f4_t acc[4];
    #pragma unroll
    for (int ns = 0; ns < 4; ns++) acc[ns] = (f4_t){0.f, 0.f, 0.f, 0.f};

    #pragma unroll
    for (int kb = 0; kb < 4; kb++) {
        float4 x = nv ? hrow[kb * 8 + quad * 2]     : zero;
        float4 y = nv ? hrow[kb * 8 + quad * 2 + 1] : zero;
        bf8_t a = pack8(x, y);
        #pragma unroll
        for (int ns = 0; ns < 4; ns++)
            acc[ns] = __builtin_amdgcn_mfma_f32_16x16x32_bf16(a, bf[kb][ns], acc[ns], 0, 0, 0);
    }

    float alv[4], arv[4];
    #pragma unroll
    for (int ns = 0; ns < 4; ns++) {
        alv[ns] = Wattn[ns * 16 + col];
        arv[ns] = Wattn[OUT_DIM + ns * 16 + col];
    }
    #pragma unroll
    for (int r = 0; r < 4; r++) {
        const int nn = n0 + quad * 4 + r;
        float pl = acc[0][r] * alv[0] + acc[1][r] * alv[1] + acc[2][r] * alv[2] + acc[3][r] * alv[3];
        float pr = acc[0][r] * arv[0] + acc[1][r] * arv[1] + acc[2][r] * arv[2] + acc[3][r] * arv[3];
        #pragma unroll
        for (int o = 1; o < 16; o <<= 1) {
            pl += __shfl_xor(pl, o, 64);
            pr += __shfl_xor(pr, o, 64);
        }
        if (nn < N) {
            __hip_bfloat16* zr = zb + (size_t)nn * OUT_DIM;
            #pragma unroll
            for (int ns = 0; ns < 4; ns++)
                zr[ns * 16 + col] = __float2bfloat16(acc[ns][r]);
            if (col == 0) { s_l[nn] = pl; s_r[nn] = pr; }
        }
    }
}

// ---------------- tail: one bucket (64 nodes) ----------------
__device__ void tail_body(int b, int t,
    const unsigned* __restrict__ tmp, const int* __restrict__ bucket_cnt,
    const float* __restrict__ s_l, const float* __restrict__ s_r,
    const uint4* __restrict__ zb4, float4* __restrict__ out4, int N,
    TailSm* sm)
{
    const int lane = t & 63;
    const int nbase = b * 64;
    int mb = bucket_cnt[b];
    if (mb > BCAP) mb = BCAP;

    if (t < 64) {
        sm->cnt_s[t] = 0;
        int n = nbase + t;
        sm->srs[t] = (n < N) ? s_r[n] : 0.f;
    }
    __syncthreads();

    const unsigned* mybuf = tmp + (size_t)b * BCAP;

    // pass A: single global read; histogram (rank) + ex, stashed in LDS
    for (int i = t; i < mb; i += 256) {
        unsigned p = mybuf[i];
        int d = p & 63u;
        int s = (p >> 6) & 0xFFFFu;
        float e = s_l[s] + sm->srs[d];
        e = (e > 0.f) ? e : NEG_SLOPE * e;
        float ex = __expf(e);
        int r = atomicAdd(&sm->cnt_s[d], 1);   // rank within node (max deg << 1024)
        if (r > 1023) r = 1023;
        sm->p2s[i] = ((unsigned)r << 22) | (p & 0x3FFFFFu);
        sm->exs[i] = ex;
    }
    __syncthreads();

    // exclusive scan of cnt_s[64] by wave 0 (shfl only)
    if (t < 64) {
        int c = sm->cnt_s[t];
        int inc = c;
        #pragma unroll
        for (int o = 1; o < 64; o <<= 1) {
            int v = __shfl_up(inc, o, 64);
            if (lane >= o) inc += v;
        }
        sm->off_s[t] = inc - c;
    }
    __syncthreads();

    // pass B: LDS -> LDS scatter into dst-sorted order
    for (int i = t; i < mb; i += 256) {
        unsigned q = sm->p2s[i];
        int d = q & 63u;
        int slot = sm->off_s[d] + (int)(q >> 22);
        if (slot < BCAP)
            sm->se[slot] = make_uint2((q >> 6) & 0xFFFFu, __float_as_uint(sm->exs[i]));
    }
    __syncthreads();

    // ---- phase 2: 8-lane group per node; no cross-lane ops ----
    const int ch8 = t & 7;       // which 16B chunk (8 bf16 channels) of the row
    const int grp = t >> 3;      // 0..31

    for (int nl = grp; nl < 64; nl += 32) {
        const int n = nbase + nl;
        if (n >= N) continue;
        const int beg = sm->off_s[nl];
        int end = beg + sm->cnt_s[nl];
        if (end > BCAP) end = BCAP;
        float4* op = out4 + (size_t)n * 16 + ch8 * 2;

        if (end <= beg) {
            op[0] = make_float4(0.f, 0.f, 0.f, 0.f);
            op[1] = make_float4(0.f, 0.f, 0.f, 0.f);
            continue;
        }

        float a0 = 0.f, a1 = 0.f, a2 = 0.f, a3 = 0.f;
        float a4 = 0.f, a5 = 0.f, a6 = 0.f, a7 = 0.f;
        float dsum = 0.f;

        #pragma unroll 4
        for (int i = beg; i < end; ++i) {
            uint2 q = sm->se[i];          // ds_read_b64, broadcast within group
            float ex = __uint_as_float(q.y);
            dsum += ex;
            uint4 zv = zb4[(size_t)q.x * 8 + ch8];
            float f0 = __uint_as_float(zv.x << 16);
            float f1 = __uint_as_float(zv.x & 0xffff0000u);
            float f2 = __uint_as_float(zv.y << 16);
            float f3 = __uint_as_float(zv.y & 0xffff0000u);
            float f4 = __uint_as_float(zv.z << 16);
            float f5 = __uint_as_float(zv.z & 0xffff0000u);
            float f6 = __uint_as_float(zv.w << 16);
            float f7 = __uint_as_float(zv.w & 0xffff0000u);
            a0 += ex * f0; a1 += ex * f1; a2 += ex * f2; a3 += ex * f3;
            a4 += ex * f4; a5 += ex * f5; a6 += ex * f6; a7 += ex * f7;
        }

        float inv = 1.f / dsum;
        op[0] = make_float4(a0 * inv, a1 * inv, a2 * inv, a3 * inv);
        op[1] = make_float4(a4 * inv, a5 * inv, a6 * inv, a7 * inv);
    }
}

// Manual device-scope grid barrier. Safe because grid <= co-resident capacity
// (sized from the occupancy API) -- every block is running, so the spin
// always terminates. Counter is zeroed by the memset before each launch.
__device__ __forceinline__ void grid_barrier(int* bar, int nblk)
{
    __syncthreads();
    if (threadIdx.x == 0) {
        __threadfence();                    // release: prior writes visible device-wide
        atomicAdd(bar, 1);
        while (__hip_atomic_load(bar, __ATOMIC_RELAXED, __HIP_MEMORY_SCOPE_AGENT) < nblk)
            __builtin_amdgcn_s_sleep(2);
        __threadfence();                    // acquire
    }
    __syncthreads();
}

// ---------------- fused kernel (normal launch, grid-stride phases) ----------------
__global__ __launch_bounds__(256) void k_fused(
    const int* __restrict__ src, const int* __restrict__ dst,
    int* __restrict__ bucket_cursor, int* __restrict__ bar,
    unsigned* __restrict__ tmp, int E,
    const float4* __restrict__ h4, const float4* __restrict__ W4,
    const float* __restrict__ Wattn,
    __hip_bfloat16* __restrict__ zb, float* __restrict__ s_l, float* __restrict__ s_r,
    float4* __restrict__ out4, int N, int NP1, int NG, int NBK)
{
    __shared__ SmU sm;
    const int t = threadIdx.x;

    // phase A: part1 blocks then gemm blocks, grid-stride
    for (int bid = blockIdx.x; bid < NP1 + NG; bid += gridDim.x) {
        if (bid < NP1)
            part1_body(bid, t, src, dst, bucket_cursor, tmp, E, sm.f.cntA, sm.f.gbase);
        else
            gemm_body(bid - NP1, t, h4, W4, Wattn, zb, s_l, s_r, N);
        __syncthreads();
    }

    grid_barrier(bar, (int)gridDim.x);

    // phase B: tail buckets, grid-stride
    for (int bid = blockIdx.x; bid < NBK; bid += gridDim.x) {
        tail_body(bid, t, tmp, bucket_cursor, s_l, s_r, (const uint4*)zb, out4, N, &sm.t);
        __syncthreads();
    }
}

// ---------------- fallback two-kernel path (r5-equivalent) ----------------
__global__ __launch_bounds__(256) void k_front(
    const int* __restrict__ src, const int* __restrict__ dst,
    int* __restrict__ bucket_cursor, unsigned* __restrict__ tmp, int E,
    const float4* __restrict__ h4, const float4* __restrict__ W4,
    const float* __restrict__ Wattn,
    __hip_bfloat16* __restrict__ zb, float* __restrict__ s_l, float* __restrict__ s_r,
    int N, int NP1)
{
    __shared__ FrontSm sm;
    const int t = threadIdx.x;
    if ((int)blockIdx.x < NP1)
        part1_body(blockIdx.x, t, src, dst, bucket_cursor, tmp, E, sm.cntA, sm.gbase);
    else
        gemm_body(blockIdx.x - NP1, t, h4, W4, Wattn, zb, s_l, s_r, N);
}

__global__ __launch_bounds__(256) void k_tail(
    const unsigned* __restrict__ tmp, const int* __restrict__ bucket_cnt,
    const float* __restrict__ s_l, const float* __restrict__ s_r,
    const uint4* __restrict__ zb4, float4* __restrict__ out4, int N)
{
    __shared__ TailSm sm;
    tail_body(blockIdx.x, threadIdx.x, tmp, bucket_cnt, s_l, s_r, zb4, out4, N, &sm);
}

extern "C" void kernel_launch(void* const* d_in, const int* in_sizes, int n_in,
                              void* d_out, int out_size, void* d_ws, size_t ws_size,
                              hipStream_t stream)
{
    const float* h     = (const float*)d_in[0];
    const float* Wfc   = (const float*)d_in[1];
    const float* Wattn = (const float*)d_in[2];
    const int*   src   = (const int*)d_in[3];
    const int*   dst   = (const int*)d_in[4];
    const int N = in_sizes[0] / IN_DIM;
    const int E = in_sizes[3];
    const int NBK = (N + 63) / 64;                      // 782 buckets
    const int NP1 = (E + 256 * EPT - 1) / (256 * EPT);  // 196 part1 blocks
    const int NG  = (N + 63) / 64;                      // 782 gemm blocks
    const int TOTAL = NP1 + NG;                         // 978

    // ws layout: z_bf16[N*64] | s_l[N] | s_r[N] | bucket_cursor[1024] | bar+pad[16] | tmp
    __hip_bfloat16* zb = (__hip_bfloat16*)d_ws;
    float* s_l     = (float*)(zb + (size_t)N * OUT_DIM);
    float* s_r     = s_l + N;
    int*   bcursor = (int*)(s_r + N);
    int*   bar     = bcursor + 1024;
    unsigned* tmp  = (unsigned*)(bcursor + 1040);       // keep 16B alignment

    hipMemsetAsync(bcursor, 0, 1040 * sizeof(int), stream);

    // co-resident capacity for the fused kernel (host query; not a stream op)
    static int s_blocks_per_cu = -2;
    if (s_blocks_per_cu == -2) {
        int nb = 0;
        hipError_t e = hipOccupancyMaxActiveBlocksPerMultiprocessor(&nb, k_fused, 256, 0);
        s_blocks_per_cu = (e == hipSuccess && nb > 0) ? nb : 0;
    }
    const int capacity = s_blocks_per_cu * 256;         // 256 CUs on MI355X

    if (capacity >= 512) {
        const int GRID = (TOTAL < capacity) ? TOTAL : capacity;
        k_fused<<<GRID, 256, 0, stream>>>(src, dst, bcursor, bar, tmp, E,
                                          (const float4*)h, (const float4*)Wfc, Wattn,
                                          zb, s_l, s_r, (float4*)d_out, N, NP1, NG, NBK);
    } else {
        k_front<<<TOTAL, 256, 0, stream>>>(src, dst, bcursor, tmp, E,
                                           (const float4*)h, (const float4*)Wfc, Wattn,
                                           zb, s_l, s_r, N, NP1);
        k_tail <<<NBK, 256, 0, stream>>>(tmp, bcursor, s_l, s_r,
                                         (const uint4*)zb, (float4*)d_out, N);
    }
}

// Round 8
// 136.549 us; speedup vs baseline: 1.0680x; 1.0680x over previous
//
#include <hip/hip_runtime.h>
#include <hip/hip_bf16.h>
#include <math.h>

#define IN_DIM 128
#define OUT_DIM 64
#define NEG_SLOPE 0.01f
#define BCAP 2048          // slots per 64-node bucket (avg fill ~1023)
#define EPT 8              // edges per thread in part1 (2048 edges/block, 391 blocks)

typedef __attribute__((ext_vector_type(8))) short bf8_t;   // 8 bf16 (4 VGPRs)
typedef __attribute__((ext_vector_type(4))) float f4_t;    // MFMA acc

__device__ __forceinline__ bf8_t pack8(float4 a, float4 b) {
    union { bf8_t v; __hip_bfloat162 h[4]; } u;
    u.h[0] = __float22bfloat162_rn(make_float2(a.x, a.y));
    u.h[1] = __float22bfloat162_rn(make_float2(a.z, a.w));
    u.h[2] = __float22bfloat162_rn(make_float2(b.x, b.y));
    u.h[3] = __float22bfloat162_rn(make_float2(b.z, b.w));
    return u.v;
}

// ---- K_front: blocks [0,NP1) = part1 (bin edges), blocks [NP1,..) = MFMA gemm ----
// payload u32 = (bucket<<22) | (src<<6) | (dst&63), bucket = dst>>6 (< 1024).
// Part1 uses ONE LDS-atomic pass: the histogram's return value is the edge's
// rank within (block,bucket); final scatter is gbase[b]+rank (no second atomic).
__global__ __launch_bounds__(256) void k_front(
    const int* __restrict__ src, const int* __restrict__ dst,
    int* __restrict__ bucket_cursor, unsigned* __restrict__ tmp, int E,
    const float4* __restrict__ h4, const float4* __restrict__ W4,
    const float* __restrict__ Wattn,
    __hip_bfloat16* __restrict__ zb, float* __restrict__ s_l, float* __restrict__ s_r,
    int N, int NP1)
{
    __shared__ int cntA[1024];
    __shared__ int gbase[1024];

    const int t = threadIdx.x;

    if (blockIdx.x < NP1) {
        // ================= part1: bin 2048 edges into buckets =================
        const int base_e = blockIdx.x * (256 * EPT);

        for (int b = t; b < 1024; b += 256) cntA[b] = 0;
        __syncthreads();

        unsigned pArr[EPT];
        unsigned short rArr[EPT];
        #pragma unroll
        for (int i = 0; i < EPT; i++) {
            int ei = base_e + i * 256 + t;
            if (ei < E) {
                int s = src[ei], d = dst[ei];
                int b = d >> 6;
                pArr[i] = ((unsigned)b << 22) | ((unsigned)s << 6) | (unsigned)(d & 63);
                rArr[i] = (unsigned short)atomicAdd(&cntA[b], 1);   // local rank
            } else {
                pArr[i] = 0xFFFFFFFFu;
            }
        }
        __syncthreads();

        for (int b = t; b < 1024; b += 256)
            if (cntA[b] > 0)
                gbase[b] = atomicAdd(&bucket_cursor[b], cntA[b]);
        __syncthreads();

        #pragma unroll
        for (int i = 0; i < EPT; i++) {
            unsigned p = pArr[i];
            if (p == 0xFFFFFFFFu) continue;
            int b = p >> 22;
            int slot = gbase[b] + rArr[i];
            if (slot < BCAP)
                tmp[(size_t)b * BCAP + slot] = p;
        }
    } else {
        // ================= gemm: MFMA, 64 nodes per block =================
        const int lane = t & 63;
        const int wv   = t >> 6;
        const int col  = lane & 15, quad = lane >> 4;
        const int n0   = (blockIdx.x - NP1) * 64 + wv * 16;
        if (n0 >= N) return;   // safe: no __syncthreads in this branch

        bf8_t bf[4][4];
        #pragma unroll
        for (int ns = 0; ns < 4; ns++) {
            const float4* wrow = W4 + (size_t)(ns * 16 + col) * (IN_DIM / 4);
            #pragma unroll
            for (int kb = 0; kb < 4; kb++) {
                float4 x = wrow[kb * 8 + quad * 2];
                float4 y = wrow[kb * 8 + quad * 2 + 1];
                bf[kb][ns] = pack8(x, y);
            }
        }

        const int  na = n0 + col;
        const bool nv = (na < N);
        const float4* hrow = h4 + (size_t)(nv ? na : 0) * (IN_DIM / 4);
        const float4 zero = make_float4(0.f, 0.f, 0.f, 0.f);

        f4_t acc[4];
        #pragma unroll
        for (int ns = 0; ns < 4; ns++) acc[ns] = (f4_t){0.f, 0.f, 0.f, 0.f};

        #pragma unroll
        for (int kb = 0; kb < 4; kb++) {
            float4 x = nv ? hrow[kb * 8 + quad * 2]     : zero;
            float4 y = nv ? hrow[kb * 8 + quad * 2 + 1] : zero;
            bf8_t a = pack8(x, y);
            #pragma unroll
            for (int ns = 0; ns < 4; ns++)
                acc[ns] = __builtin_amdgcn_mfma_f32_16x16x32_bf16(a, bf[kb][ns], acc[ns], 0, 0, 0);
        }

        float alv[4], arv[4];
        #pragma unroll
        for (int ns = 0; ns < 4; ns++) {
            alv[ns] = Wattn[ns * 16 + col];
            arv[ns] = Wattn[OUT_DIM + ns * 16 + col];
        }
        #pragma unroll
        for (int r = 0; r < 4; r++) {
            const int nn = n0 + quad * 4 + r;
            float pl = acc[0][r] * alv[0] + acc[1][r] * alv[1] + acc[2][r] * alv[2] + acc[3][r] * alv[3];
            float pr = acc[0][r] * arv[0] + acc[1][r] * arv[1] + acc[2][r] * arv[2] + acc[3][r] * arv[3];
            #pragma unroll
            for (int o = 1; o < 16; o <<= 1) {
                pl += __shfl_xor(pl, o, 64);
                pr += __shfl_xor(pr, o, 64);
            }
            if (nn < N) {
                __hip_bfloat16* zr = zb + (size_t)nn * OUT_DIM;
                #pragma unroll
                for (int ns = 0; ns < 4; ns++)
                    zr[ns * 16 + col] = __float2bfloat16(acc[ns][r]);
                if (col == 0) { s_l[nn] = pl; s_r[nn] = pr; }
            }
        }
    }
}

// ---- K_tail: one block per 64-node bucket.
// Phase 1 (single global pass): read slab once; compute ex; rank from the
// histogram atomic; stash (rank|src|d) + ex in LDS. After the wave-0 scan,
// pass B scatters LDS->LDS (no global re-read, no second expf).
// Phase 2: one 8-lane group per node; unroll-4 gather MLP; dsum in registers.
__global__ __launch_bounds__(256) void k_tail(
    const unsigned* __restrict__ tmp, const int* __restrict__ bucket_cnt,
    const float* __restrict__ s_l, const float* __restrict__ s_r,
    const uint4* __restrict__ zb4, float4* __restrict__ out4, int N)
{
    __shared__ uint2 se[BCAP];               // 16 KB: {src, ex bits}
    __shared__ unsigned p2s[BCAP];           // 8 KB: (rank<<22)|(src<<6)|d
    __shared__ float exs[BCAP];              // 8 KB
    __shared__ int cnt_s[64], off_s[64];
    __shared__ float srs[64];

    const int b = blockIdx.x, t = threadIdx.x;
    const int lane = t & 63;
    const int nbase = b * 64;
    int mb = bucket_cnt[b];
    if (mb > BCAP) mb = BCAP;

    if (t < 64) {
        cnt_s[t] = 0;
        int n = nbase + t;
        srs[t] = (n < N) ? s_r[n] : 0.f;
    }
    __syncthreads();

    const unsigned* mybuf = tmp + (size_t)b * BCAP;

    // pass A: single global read; histogram (rank) + ex, stashed in LDS
    for (int i = t; i < mb; i += 256) {
        unsigned p = mybuf[i];
        int d = p & 63u;
        int s = (p >> 6) & 0xFFFFu;
        float e = s_l[s] + srs[d];
        e = (e > 0.f) ? e : NEG_SLOPE * e;
        float ex = __expf(e);
        int r = atomicAdd(&cnt_s[d], 1);     // rank within node (max deg << 1024)
        if (r > 1023) r = 1023;
        p2s[i] = ((unsigned)r << 22) | (p & 0x3FFFFFu);
        exs[i] = ex;
    }
    __syncthreads();

    // exclusive scan of cnt_s[64] by wave 0 (shfl only)
    if (t < 64) {
        int c = cnt_s[t];
        int inc = c;
        #pragma unroll
        for (int o = 1; o < 64; o <<= 1) {
            int v = __shfl_up(inc, o, 64);
            if (lane >= o) inc += v;
        }
        off_s[t] = inc - c;
    }
    __syncthreads();

    // pass B: LDS -> LDS scatter into dst-sorted order
    for (int i = t; i < mb; i += 256) {
        unsigned q = p2s[i];
        int d = q & 63u;
        int slot = off_s[d] + (int)(q >> 22);
        if (slot < BCAP)
            se[slot] = make_uint2((q >> 6) & 0xFFFFu, __float_as_uint(exs[i]));
    }
    __syncthreads();

    // ---- phase 2: 8-lane group per node; no cross-lane ops ----
    const int ch8 = t & 7;       // which 16B chunk (8 bf16 channels) of the row
    const int grp = t >> 3;      // 0..31

    for (int nl = grp; nl < 64; nl += 32) {
        const int n = nbase + nl;
        if (n >= N) continue;
        const int beg = off_s[nl];
        int end = beg + cnt_s[nl];
        if (end > BCAP) end = BCAP;
        float4* op = out4 + (size_t)n * 16 + ch8 * 2;

        if (end <= beg) {
            op[0] = make_float4(0.f, 0.f, 0.f, 0.f);
            op[1] = make_float4(0.f, 0.f, 0.f, 0.f);
            continue;
        }

        float a0 = 0.f, a1 = 0.f, a2 = 0.f, a3 = 0.f;
        float a4 = 0.f, a5 = 0.f, a6 = 0.f, a7 = 0.f;
        float dsum = 0.f;

        #pragma unroll 4
        for (int i = beg; i < end; ++i) {
            uint2 q = se[i];              // ds_read_b64, broadcast within group
            float ex = __uint_as_float(q.y);
            dsum += ex;
            uint4 zv = zb4[(size_t)q.x * 8 + ch8];
            float f0 = __uint_as_float(zv.x << 16);
            float f1 = __uint_as_float(zv.x & 0xffff0000u);
            float f2 = __uint_as_float(zv.y << 16);
            float f3 = __uint_as_float(zv.y & 0xffff0000u);
            float f4 = __uint_as_float(zv.z << 16);
            float f5 = __uint_as_float(zv.z & 0xffff0000u);
            float f6 = __uint_as_float(zv.w << 16);
            float f7 = __uint_as_float(zv.w & 0xffff0000u);
            a0 += ex * f0; a1 += ex * f1; a2 += ex * f2; a3 += ex * f3;
            a4 += ex * f4; a5 += ex * f5; a6 += ex * f6; a7 += ex * f7;
        }

        float inv = 1.f / dsum;
        op[0] = make_float4(a0 * inv, a1 * inv, a2 * inv, a3 * inv);
        op[1] = make_float4(a4 * inv, a5 * inv, a6 * inv, a7 * inv);
    }
}

extern "C" void kernel_launch(void* const* d_in, const int* in_sizes, int n_in,
                              void* d_out, int out_size, void* d_ws, size_t ws_size,
                              hipStream_t stream)
{
    const float* h     = (const float*)d_in[0];
    const float* Wfc   = (const float*)d_in[1];
    const float* Wattn = (const float*)d_in[2];
    const int*   src   = (const int*)d_in[3];
    const int*   dst   = (const int*)d_in[4];
    const int N = in_sizes[0] / IN_DIM;
    const int E = in_sizes[3];
    const int NBK = (N + 63) / 64;                      // 782 buckets
    const int NP1 = (E + 256 * EPT - 1) / (256 * EPT);  // 391 part1 blocks

    // ws layout: z_bf16[N*64] | s_l[N] | s_r[N] | bucket_cursor[1024] | tmp[NBK*BCAP]
    __hip_bfloat16* zb = (__hip_bfloat16*)d_ws;
    float* s_l     = (float*)(zb + (size_t)N * OUT_DIM);
    float* s_r     = s_l + N;
    int*   bcursor = (int*)(s_r + N);
    unsigned* tmp  = (unsigned*)(bcursor + 1024);

    const int nblk_g = (N + 63) / 64;                   // 782 gemm blocks

    hipMemsetAsync(bcursor, 0, 1024 * sizeof(int), stream);

    k_front<<<NP1 + nblk_g, 256, 0, stream>>>(src, dst, bcursor, tmp, E,
                                              (const float4*)h, (const float4*)Wfc, Wattn,
                                              zb, s_l, s_r, N, NP1);
    k_tail <<<NBK, 256, 0, stream>>>(tmp, bcursor, s_l, s_r,
                                     (const uint4*)zb, (float4*)d_out, N);
}

// Round 9
// 132.953 us; speedup vs baseline: 1.0969x; 1.0270x over previous
//
#include <hip/hip_runtime.h>
#include <hip/hip_bf16.h>
#include <math.h>

#define IN_DIM 128
#define OUT_DIM 64
#define NEG_SLOPE 0.01f
#define BCAP 2048          // slots per 64-node bucket (avg fill ~1023)
#define EPT 16             // edges per thread in part1 (4096 edges/block) — bracketed optimum {8,16,32}

typedef __attribute__((ext_vector_type(8))) short bf8_t;   // 8 bf16 (4 VGPRs)
typedef __attribute__((ext_vector_type(4))) float f4_t;    // MFMA acc

__device__ __forceinline__ bf8_t pack8(float4 a, float4 b) {
    union { bf8_t v; __hip_bfloat162 h[4]; } u;
    u.h[0] = __float22bfloat162_rn(make_float2(a.x, a.y));
    u.h[1] = __float22bfloat162_rn(make_float2(a.z, a.w));
    u.h[2] = __float22bfloat162_rn(make_float2(b.x, b.y));
    u.h[3] = __float22bfloat162_rn(make_float2(b.z, b.w));
    return u.v;
}

// ---- K_front: blocks [0,NP1) = part1 (bin edges), blocks [NP1,..) = MFMA gemm ----
// payload u32 = (bucket<<22) | (src<<6) | (dst&63), bucket = dst>>6 (< 1024).
// Part1 uses ONE LDS-atomic pass: the histogram's return value is the edge's
// rank within (block,bucket); final scatter is gbase[b]+rank (no second atomic).
__global__ __launch_bounds__(256) void k_front(
    const int* __restrict__ src, const int* __restrict__ dst,
    int* __restrict__ bucket_cursor, unsigned* __restrict__ tmp, int E,
    const float4* __restrict__ h4, const float4* __restrict__ W4,
    const float* __restrict__ Wattn,
    __hip_bfloat16* __restrict__ zb, float* __restrict__ s_l, float* __restrict__ s_r,
    int N, int NP1)
{
    __shared__ int cntA[1024];
    __shared__ int gbase[1024];

    const int t = threadIdx.x;

    if (blockIdx.x < NP1) {
        // ================= part1: bin 4096 edges into buckets =================
        const int base_e = blockIdx.x * (256 * EPT);

        for (int b = t; b < 1024; b += 256) cntA[b] = 0;
        __syncthreads();

        unsigned pArr[EPT];
        unsigned short rArr[EPT];
        #pragma unroll
        for (int i = 0; i < EPT; i++) {
            int ei = base_e + i * 256 + t;
            if (ei < E) {
                int s = src[ei], d = dst[ei];
                int b = d >> 6;
                pArr[i] = ((unsigned)b << 22) | ((unsigned)s << 6) | (unsigned)(d & 63);
                rArr[i] = (unsigned short)atomicAdd(&cntA[b], 1);   // local rank
            } else {
                pArr[i] = 0xFFFFFFFFu;
            }
        }
        __syncthreads();

        for (int b = t; b < 1024; b += 256)
            if (cntA[b] > 0)
                gbase[b] = atomicAdd(&bucket_cursor[b], cntA[b]);
        __syncthreads();

        #pragma unroll
        for (int i = 0; i < EPT; i++) {
            unsigned p = pArr[i];
            if (p == 0xFFFFFFFFu) continue;
            int b = p >> 22;
            int slot = gbase[b] + rArr[i];
            if (slot < BCAP)
                tmp[(size_t)b * BCAP + slot] = p;
        }
    } else {
        // ================= gemm: MFMA, 64 nodes per block =================
        const int lane = t & 63;
        const int wv   = t >> 6;
        const int col  = lane & 15, quad = lane >> 4;
        const int n0   = (blockIdx.x - NP1) * 64 + wv * 16;
        if (n0 >= N) return;   // safe: no __syncthreads in this branch

        bf8_t bf[4][4];
        #pragma unroll
        for (int ns = 0; ns < 4; ns++) {
            const float4* wrow = W4 + (size_t)(ns * 16 + col) * (IN_DIM / 4);
            #pragma unroll
            for (int kb = 0; kb < 4; kb++) {
                float4 x = wrow[kb * 8 + quad * 2];
                float4 y = wrow[kb * 8 + quad * 2 + 1];
                bf[kb][ns] = pack8(x, y);
            }
        }

        const int  na = n0 + col;
        const bool nv = (na < N);
        const float4* hrow = h4 + (size_t)(nv ? na : 0) * (IN_DIM / 4);
        const float4 zero = make_float4(0.f, 0.f, 0.f, 0.f);

        f4_t acc[4];
        #pragma unroll
        for (int ns = 0; ns < 4; ns++) acc[ns] = (f4_t){0.f, 0.f, 0.f, 0.f};

        #pragma unroll
        for (int kb = 0; kb < 4; kb++) {
            float4 x = nv ? hrow[kb * 8 + quad * 2]     : zero;
            float4 y = nv ? hrow[kb * 8 + quad * 2 + 1] : zero;
            bf8_t a = pack8(x, y);
            #pragma unroll
            for (int ns = 0; ns < 4; ns++)
                acc[ns] = __builtin_amdgcn_mfma_f32_16x16x32_bf16(a, bf[kb][ns], acc[ns], 0, 0, 0);
        }

        float alv[4], arv[4];
        #pragma unroll
        for (int ns = 0; ns < 4; ns++) {
            alv[ns] = Wattn[ns * 16 + col];
            arv[ns] = Wattn[OUT_DIM + ns * 16 + col];
        }
        #pragma unroll
        for (int r = 0; r < 4; r++) {
            const int nn = n0 + quad * 4 + r;
            float pl = acc[0][r] * alv[0] + acc[1][r] * alv[1] + acc[2][r] * alv[2] + acc[3][r] * alv[3];
            float pr = acc[0][r] * arv[0] + acc[1][r] * arv[1] + acc[2][r] * arv[2] + acc[3][r] * arv[3];
            #pragma unroll
            for (int o = 1; o < 16; o <<= 1) {
                pl += __shfl_xor(pl, o, 64);
                pr += __shfl_xor(pr, o, 64);
            }
            if (nn < N) {
                __hip_bfloat16* zr = zb + (size_t)nn * OUT_DIM;
                #pragma unroll
                for (int ns = 0; ns < 4; ns++)
                    zr[ns * 16 + col] = __float2bfloat16(acc[ns][r]);
                if (col == 0) { s_l[nn] = pl; s_r[nn] = pr; }
            }
        }
    }
}

// ---- K_tail: one block per 64-node bucket.
// Phase 1 (single global pass): read slab once; compute ex; rank from the
// histogram atomic; stash (rank|src|d) + ex in LDS. After the wave-0 scan,
// pass B scatters LDS->LDS (no global re-read, no second expf).
// Phase 2: one 8-lane group per node; unroll-4 gather MLP; dsum in registers.
__global__ __launch_bounds__(256) void k_tail(
    const unsigned* __restrict__ tmp, const int* __restrict__ bucket_cnt,
    const float* __restrict__ s_l, const float* __restrict__ s_r,
    const uint4* __restrict__ zb4, float4* __restrict__ out4, int N)
{
    __shared__ uint2 se[BCAP];               // 16 KB: {src, ex bits}
    __shared__ unsigned p2s[BCAP];           // 8 KB: (rank<<22)|(src<<6)|d
    __shared__ float exs[BCAP];              // 8 KB
    __shared__ int cnt_s[64], off_s[64];
    __shared__ float srs[64];

    const int b = blockIdx.x, t = threadIdx.x;
    const int lane = t & 63;
    const int nbase = b * 64;
    int mb = bucket_cnt[b];
    if (mb > BCAP) mb = BCAP;

    if (t < 64) {
        cnt_s[t] = 0;
        int n = nbase + t;
        srs[t] = (n < N) ? s_r[n] : 0.f;
    }
    __syncthreads();

    const unsigned* mybuf = tmp + (size_t)b * BCAP;

    // pass A: single global read; histogram (rank) + ex, stashed in LDS
    for (int i = t; i < mb; i += 256) {
        unsigned p = mybuf[i];
        int d = p & 63u;
        int s = (p >> 6) & 0xFFFFu;
        float e = s_l[s] + srs[d];
        e = (e > 0.f) ? e : NEG_SLOPE * e;
        float ex = __expf(e);
        int r = atomicAdd(&cnt_s[d], 1);     // rank within node (max deg << 1024)
        if (r > 1023) r = 1023;
        p2s[i] = ((unsigned)r << 22) | (p & 0x3FFFFFu);
        exs[i] = ex;
    }
    __syncthreads();

    // exclusive scan of cnt_s[64] by wave 0 (shfl only)
    if (t < 64) {
        int c = cnt_s[t];
        int inc = c;
        #pragma unroll
        for (int o = 1; o < 64; o <<= 1) {
            int v = __shfl_up(inc, o, 64);
            if (lane >= o) inc += v;
        }
        off_s[t] = inc - c;
    }
    __syncthreads();

    // pass B: LDS -> LDS scatter into dst-sorted order
    for (int i = t; i < mb; i += 256) {
        unsigned q = p2s[i];
        int d = q & 63u;
        int slot = off_s[d] + (int)(q >> 22);
        if (slot < BCAP)
            se[slot] = make_uint2((q >> 6) & 0xFFFFu, __float_as_uint(exs[i]));
    }
    __syncthreads();

    // ---- phase 2: 8-lane group per node; no cross-lane ops ----
    const int ch8 = t & 7;       // which 16B chunk (8 bf16 channels) of the row
    const int grp = t >> 3;      // 0..31

    for (int nl = grp; nl < 64; nl += 32) {
        const int n = nbase + nl;
        if (n >= N) continue;
        const int beg = off_s[nl];
        int end = beg + cnt_s[nl];
        if (end > BCAP) end = BCAP;
        float4* op = out4 + (size_t)n * 16 + ch8 * 2;

        if (end <= beg) {
            op[0] = make_float4(0.f, 0.f, 0.f, 0.f);
            op[1] = make_float4(0.f, 0.f, 0.f, 0.f);
            continue;
        }

        float a0 = 0.f, a1 = 0.f, a2 = 0.f, a3 = 0.f;
        float a4 = 0.f, a5 = 0.f, a6 = 0.f, a7 = 0.f;
        float dsum = 0.f;

        #pragma unroll 4
        for (int i = beg; i < end; ++i) {
            uint2 q = se[i];              // ds_read_b64, broadcast within group
            float ex = __uint_as_float(q.y);
            dsum += ex;
            uint4 zv = zb4[(size_t)q.x * 8 + ch8];
            float f0 = __uint_as_float(zv.x << 16);
            float f1 = __uint_as_float(zv.x & 0xffff0000u);
            float f2 = __uint_as_float(zv.y << 16);
            float f3 = __uint_as_float(zv.y & 0xffff0000u);
            float f4 = __uint_as_float(zv.z << 16);
            float f5 = __uint_as_float(zv.z & 0xffff0000u);
            float f6 = __uint_as_float(zv.w << 16);
            float f7 = __uint_as_float(zv.w & 0xffff0000u);
            a0 += ex * f0; a1 += ex * f1; a2 += ex * f2; a3 += ex * f3;
            a4 += ex * f4; a5 += ex * f5; a6 += ex * f6; a7 += ex * f7;
        }

        float inv = 1.f / dsum;
        op[0] = make_float4(a0 * inv, a1 * inv, a2 * inv, a3 * inv);
        op[1] = make_float4(a4 * inv, a5 * inv, a6 * inv, a7 * inv);
    }
}

extern "C" void kernel_launch(void* const* d_in, const int* in_sizes, int n_in,
                              void* d_out, int out_size, void* d_ws, size_t ws_size,
                              hipStream_t stream)
{
    const float* h     = (const float*)d_in[0];
    const float* Wfc   = (const float*)d_in[1];
    const float* Wattn = (const float*)d_in[2];
    const int*   src   = (const int*)d_in[3];
    const int*   dst   = (const int*)d_in[4];
    const int N = in_sizes[0] / IN_DIM;
    const int E = in_sizes[3];
    const int NBK = (N + 63) / 64;                      // 782 buckets
    const int NP1 = (E + 256 * EPT - 1) / (256 * EPT);  // 196 part1 blocks

    // ws layout: z_bf16[N*64] | s_l[N] | s_r[N] | bucket_cursor[1024] | tmp[NBK*BCAP]
    __hip_bfloat16* zb = (__hip_bfloat16*)d_ws;
    float* s_l     = (float*)(zb + (size_t)N * OUT_DIM);
    float* s_r     = s_l + N;
    int*   bcursor = (int*)(s_r + N);
    unsigned* tmp  = (unsigned*)(bcursor + 1024);

    const int nblk_g = (N + 63) / 64;                   // 782 gemm blocks

    hipMemsetAsync(bcursor, 0, 1024 * sizeof(int), stream);

    k_front<<<NP1 + nblk_g, 256, 0, stream>>>(src, dst, bcursor, tmp, E,
                                              (const float4*)h, (const float4*)Wfc, Wattn,
                                              zb, s_l, s_r, N, NP1);
    k_tail <<<NBK, 256, 0, stream>>>(tmp, bcursor, s_l, s_r,
                                     (const uint4*)zb, (float4*)d_out, N);
}